// Round 20
// baseline (106.139 us; speedup 1.0000x reference)
//
#include <hip/hip_runtime.h>

#define FFT_N 4096
#define NT    256
// skew in 16-byte units: +1 per 16 (r12-verified layout: conflicts ~1e6, negligible)
#define SK(i) ((i) + ((i) >> 4))
// base-4 digit-reverse involution for 16: P(m) = ((m&3)<<2)|(m>>2)
#define PM(m) ((((m) & 3) << 2) | ((m) >> 2))

typedef float  f2 __attribute__((ext_vector_type(2)));  // lane = row pair: (rowX, rowX+1)
typedef __fp16 h8 __attribute__((ext_vector_type(8)));  // LDS: re01,re23,im01,im23

__device__ __forceinline__ f2 mk2(float a, float b) { f2 v; v.x = a; v.y = b; return v; }
__device__ __forceinline__ h8 packh8(f2 ra, f2 rb, f2 ia, f2 ib) {
    h8 v;
    v[0] = (__fp16)ra.x; v[1] = (__fp16)ra.y; v[2] = (__fp16)rb.x; v[3] = (__fp16)rb.y;
    v[4] = (__fp16)ia.x; v[5] = (__fp16)ia.y; v[6] = (__fp16)ib.x; v[7] = (__fp16)ib.y;
    return v;
}

// In-place 16-point DFT, SoA over a row pair: re[m]/im[m] = (row0,row1) packed VOP3P.
// Math verified r18/r19. PERMIN=false: natural in, slot m = freq PM(m). PERMIN=true: mirrored.
template <int SGN, bool PERMIN>
__device__ __forceinline__ void ip16(f2* re, f2* im) {
    const float C1 = 0.92387953251128675613f;   // cos(pi/8)
    const float S1 = 0.38268343236508977173f;   // sin(pi/8)
    const float R2 = 0.70710678118654752440f;   // sqrt(2)/2
#define BF4(i0, i1, i2, i3) do { \
        f2 t0r = re[i0] + re[i2], t0i = im[i0] + im[i2]; \
        f2 t1r = re[i0] - re[i2], t1i = im[i0] - im[i2]; \
        f2 t2r = re[i1] + re[i3], t2i = im[i1] + im[i3]; \
        f2 t3r = re[i1] - re[i3], t3i = im[i1] - im[i3]; \
        re[i0] = t0r + t2r; im[i0] = t0i + t2i; \
        re[i2] = t0r - t2r; im[i2] = t0i - t2i; \
        if (SGN < 0) { re[i1] = t1r + t3i; im[i1] = t1i - t3r; \
                       re[i3] = t1r - t3i; im[i3] = t1i + t3r; } \
        else         { re[i1] = t1r - t3i; im[i1] = t1i + t3r; \
                       re[i3] = t1r + t3i; im[i3] = t1i - t3r; } \
    } while (0)
#define TWM(m, cr, ci) do { \
        f2 rr_ = re[m], ii_ = im[m]; \
        if (SGN < 0) { re[m] = rr_ * (cr) + ii_ * (ci); im[m] = ii_ * (cr) - rr_ * (ci); } \
        else         { re[m] = rr_ * (cr) - ii_ * (ci); im[m] = ii_ * (cr) + rr_ * (ci); } \
    } while (0)
    if (!PERMIN) { BF4(0, 4, 8, 12); BF4(1, 5, 9, 13); BF4(2, 6, 10, 14); BF4(3, 7, 11, 15); }
    else         { BF4(0, 1, 2, 3);  BF4(4, 5, 6, 7);  BF4(8, 9, 10, 11); BF4(12, 13, 14, 15); }
    TWM(5,  C1, S1);    // w1
    TWM(6,  R2, R2);    // w2
    TWM(7,  S1, C1);    // w3
    TWM(9,  R2, R2);    // w2
    {   // x[10] *= S*i
        f2 rr_ = re[10], ii_ = im[10];
        if (SGN < 0) { re[10] = ii_; im[10] = mk2(0.f, 0.f) - rr_; }
        else         { re[10] = mk2(0.f, 0.f) - ii_; im[10] = rr_; }
    }
    TWM(11, -R2, R2);   // w6
    TWM(13, S1, C1);    // w3
    TWM(14, -R2, R2);   // w6
    TWM(15, -C1, -S1);  // w9
    if (!PERMIN) { BF4(0, 1, 2, 3);  BF4(4, 5, 6, 7);  BF4(8, 9, 10, 11); BF4(12, 13, 14, 15); }
    else         { BF4(0, 4, 8, 12); BF4(1, 5, 9, 13); BF4(2, 6, 10, 14); BF4(3, 7, 11, 15); }
#undef BF4
#undef TWM
}

typedef float cplx __attribute__((ext_vector_type(2)));
// d_ws: twA[4096] = W4096^(t*r) at [r*256+t]; twB[256] = W256^(j*r) at [r*16+j]
__global__ void twiddle_init(cplx* __restrict__ twA, cplx* __restrict__ twB) {
    int m = blockIdx.x * NT + threadIdx.x;   // 0..4351
    if (m >= 4352) return;
    float s, c;
    if (m < 4096) {
        int r = m >> 8, t = m & 255;
        sincosf(-6.28318530717958647692f * (float)(t * r) / 4096.0f, &s, &c);
        cplx v; v.x = c; v.y = s; twA[m] = v;
    } else {
        int k = m - 4096;                    // k = r*16 + j
        int r = k >> 4, j = k & 15;
        sincosf(-6.28318530717958647692f * (float)(j * r) / 256.0f, &s, &c);
        cplx v; v.x = c; v.y = s; twB[k] = v;
    }
}

__global__ __launch_bounds__(NT) void circconv4096_kernel(
    const float* __restrict__ A, const float* __restrict__ Bv,
    float* __restrict__ O,
    const cplx* __restrict__ twA, const cplx* __restrict__ twB)
{
    // FOUR rows per block, packed 8xf16 per element (b128): 69.6 KB -> 2 blocks/CU.
    // Two independent f2-chains per thread (rows 0-1 and rows 2-3) = in-thread ILP.
    __shared__ h8 Z[SK(4095) + 1];
    const int t = threadIdx.x;
    const size_t r0 = (size_t)blockIdx.x * 4;
    const float* a0 = A + r0 * FFT_N;
    const float* b0 = Bv + r0 * FFT_N;
    const float* a1 = a0 + FFT_N;
    const float* b1 = b0 + FFT_N;
    const float* a2 = a0 + 2 * FFT_N;
    const float* b2 = b0 + 2 * FFT_N;
    const float* a3 = a0 + 3 * FFT_N;
    const float* b3 = b0 + 3 * FFT_N;
    float* o0 = O + r0 * FFT_N;
    float* o1 = o0 + FFT_N;
    float* o2 = o0 + 2 * FFT_N;
    float* o3 = o0 + 3 * FFT_N;

    f2 rea[16], ima[16], reb[16], imb[16];

#define TWF(RE, IM, m, w) do { f2 rr_ = RE[m], ii_ = IM[m]; float wr_ = (w).x, wi_ = (w).y; \
        RE[m] = rr_ * wr_ - ii_ * wi_; IM[m] = rr_ * wi_ + ii_ * wr_; } while (0)
#define TWC(RE, IM, m, w) do { f2 rr_ = RE[m], ii_ = IM[m]; float wr_ = (w).x, wi_ = (w).y; \
        RE[m] = rr_ * wr_ + ii_ * wi_; IM[m] = ii_ * wr_ - rr_ * wi_; } while (0)

    // ---- fwd stage 1 (stride 256): coalesced loads, all four rows ----
#pragma unroll
    for (int q = 0; q < 16; ++q) {
        int g = t + 256 * q;
        rea[q] = mk2(a0[g], a1[g]);
        ima[q] = mk2(b0[g], b1[g]);
        reb[q] = mk2(a2[g], a3[g]);
        imb[q] = mk2(b2[g], b3[g]);
    }
    ip16<-1, false>(rea, ima);
    ip16<-1, false>(reb, imb);
#pragma unroll
    for (int m = 1; m < 16; ++m) {
        cplx w = twA[PM(m) * 256 + t];
        TWF(rea, ima, m, w);
        TWF(reb, imb, m, w);
    }
#pragma unroll
    for (int m = 0; m < 16; ++m) Z[SK(t + 256 * PM(m))] = packh8(rea[m], reb[m], ima[m], imb[m]);
    __syncthreads();

    // ---- middle stages wave-private: wave w owns elements [1024w, 1024w+1024) ----
    const int j = t & 15;
    const int base = ((t >> 4) << 8) + j;

    // ---- fwd stage 2 (stride 16) ----
#pragma unroll
    for (int q = 0; q < 16; ++q) {
        h8 v = Z[SK(base + 16 * q)];
        rea[q] = mk2((float)v[0], (float)v[1]); reb[q] = mk2((float)v[2], (float)v[3]);
        ima[q] = mk2((float)v[4], (float)v[5]); imb[q] = mk2((float)v[6], (float)v[7]);
    }
    ip16<-1, false>(rea, ima);
    ip16<-1, false>(reb, imb);
#pragma unroll
    for (int m = 1; m < 16; ++m) {
        cplx w = twB[PM(m) * 16 + j];
        TWF(rea, ima, m, w);
        TWF(reb, imb, m, w);
    }
    __builtin_amdgcn_wave_barrier();
#pragma unroll
    for (int m = 0; m < 16; ++m) Z[SK(base + 16 * PM(m))] = packh8(rea[m], reb[m], ima[m], imb[m]);
    __builtin_amdgcn_wave_barrier();

    // ---- fwd stage 3 (contig) + scaled square + inv stage 1 (contig) ----
    {
        const int b3i = t * 16;
        const float s = 1.0f / 8192.0f;   // fold /4096 (ifft) and /2 (imag trick)
#pragma unroll
        for (int q = 0; q < 16; ++q) {
            h8 v = Z[SK(b3i + q)];
            rea[q] = mk2((float)v[0], (float)v[1]); reb[q] = mk2((float)v[2], (float)v[3]);
            ima[q] = mk2((float)v[4], (float)v[5]); imb[q] = mk2((float)v[6], (float)v[7]);
        }
        ip16<-1, false>(rea, ima);
        ip16<-1, false>(reb, imb);
#pragma unroll
        for (int m = 0; m < 16; ++m) {
            f2 r = rea[m], i = ima[m];
            rea[m] = (r * r - i * i) * s;
            ima[m] = (r * i) * (2.0f * s);
            r = reb[m]; i = imb[m];
            reb[m] = (r * r - i * i) * s;
            imb[m] = (r * i) * (2.0f * s);
        }
        ip16<1, true>(rea, ima);
        ip16<1, true>(reb, imb);
        __builtin_amdgcn_wave_barrier();
#pragma unroll
        for (int q = 0; q < 16; ++q) Z[SK(b3i + q)] = packh8(rea[q], reb[q], ima[q], imb[q]);
        __builtin_amdgcn_wave_barrier();
    }

    // ---- inv stage 2 (stride 16): conj twiddle, inverse dft ----
#pragma unroll
    for (int q = 0; q < 16; ++q) {
        h8 v = Z[SK(base + 16 * q)];
        rea[q] = mk2((float)v[0], (float)v[1]); reb[q] = mk2((float)v[2], (float)v[3]);
        ima[q] = mk2((float)v[4], (float)v[5]); imb[q] = mk2((float)v[6], (float)v[7]);
    }
#pragma unroll
    for (int q = 1; q < 16; ++q) {
        cplx w = twB[q * 16 + j];
        TWC(rea, ima, q, w);
        TWC(reb, imb, q, w);
    }
    ip16<1, false>(rea, ima);
    ip16<1, false>(reb, imb);
    __builtin_amdgcn_wave_barrier();
#pragma unroll
    for (int m = 0; m < 16; ++m) Z[SK(base + 16 * PM(m))] = packh8(rea[m], reb[m], ima[m], imb[m]);
    __syncthreads();   // next stage is stride-256: cross-wave

    // ---- inv stage 3 (stride 256) + coalesced store (normalization folded) ----
#pragma unroll
    for (int q = 0; q < 16; ++q) {
        h8 v = Z[SK(t + 256 * q)];
        rea[q] = mk2((float)v[0], (float)v[1]); reb[q] = mk2((float)v[2], (float)v[3]);
        ima[q] = mk2((float)v[4], (float)v[5]); imb[q] = mk2((float)v[6], (float)v[7]);
    }
#pragma unroll
    for (int q = 1; q < 16; ++q) {
        cplx w = twA[q * 256 + t];
        TWC(rea, ima, q, w);
        TWC(reb, imb, q, w);
    }
    ip16<1, false>(rea, ima);
    ip16<1, false>(reb, imb);
#pragma unroll
    for (int m = 0; m < 16; ++m) {
        int idx = t + 256 * PM(m);
        o0[idx] = ima[m].x;
        o1[idx] = ima[m].y;
        o2[idx] = imb[m].x;
        o3[idx] = imb[m].y;
    }
#undef TWF
#undef TWC
}

extern "C" void kernel_launch(void* const* d_in, const int* in_sizes, int n_in,
                              void* d_out, int out_size, void* d_ws, size_t ws_size,
                              hipStream_t stream) {
    const float* a = (const float*)d_in[0];
    const float* b = (const float*)d_in[1];
    float* out = (float*)d_out;
    cplx* twA = (cplx*)d_ws;              // 4096 cplx
    cplx* twB = twA + 4096;               // 256 cplx  (total 34 KB)
    const int B = in_sizes[0] / FFT_N;    // 8192 rows

    twiddle_init<<<17, NT, 0, stream>>>(twA, twB);        // 4352 entries
    circconv4096_kernel<<<B / 4, NT, 0, stream>>>(a, b, out, twA, twB);
}

// Round 21
// 105.277 us; speedup vs baseline: 1.0082x; 1.0082x over previous
//
#include <hip/hip_runtime.h>

#define FFT_N 4096
#define NT    256
// XOR swizzle (involution, zero padding): flips low-4 slot bits with mid bits.
// Conflict-free for all three access patterns at b64/16-lane granularity:
//  stride-256: (t&15)^(t>>4); stride-16: j^q; contig: q^(t&15).
#define XS(i) ((i) ^ (((i) >> 4) & 15))
// base-4 digit-reverse involution for 16: P(m) = ((m&3)<<2)|(m>>2)
#define PM(m) ((((m) & 3) << 2) | ((m) >> 2))

typedef float  f2 __attribute__((ext_vector_type(2)));  // lane = row: (row0, row1)
typedef __fp16 h4 __attribute__((ext_vector_type(4)));  // LDS: re0, re1, im0, im1

__device__ __forceinline__ f2 mk2(float a, float b) { f2 v; v.x = a; v.y = b; return v; }
__device__ __forceinline__ h4 packh(f2 re, f2 im) {
    h4 v; v.x = (__fp16)re.x; v.y = (__fp16)re.y; v.z = (__fp16)im.x; v.w = (__fp16)im.y;
    return v;
}

// In-place 16-point DFT, SoA over rows: re[m]/im[m] are (row0,row1) pairs.
// Every add/sub/mul is a packed VOP3P op covering both rows (verified r18/r19).
// PERMIN=false: natural in, slot m holds freq PM(m). PERMIN=true: mirrored.
template <int SGN, bool PERMIN>
__device__ __forceinline__ void ip16(f2* re, f2* im) {
    const float C1 = 0.92387953251128675613f;   // cos(pi/8)
    const float S1 = 0.38268343236508977173f;   // sin(pi/8)
    const float R2 = 0.70710678118654752440f;   // sqrt(2)/2
#define BF4(i0, i1, i2, i3) do { \
        f2 t0r = re[i0] + re[i2], t0i = im[i0] + im[i2]; \
        f2 t1r = re[i0] - re[i2], t1i = im[i0] - im[i2]; \
        f2 t2r = re[i1] + re[i3], t2i = im[i1] + im[i3]; \
        f2 t3r = re[i1] - re[i3], t3i = im[i1] - im[i3]; \
        re[i0] = t0r + t2r; im[i0] = t0i + t2i; \
        re[i2] = t0r - t2r; im[i2] = t0i - t2i; \
        if (SGN < 0) { re[i1] = t1r + t3i; im[i1] = t1i - t3r; \
                       re[i3] = t1r - t3i; im[i3] = t1i + t3r; } \
        else         { re[i1] = t1r - t3i; im[i1] = t1i + t3r; \
                       re[i3] = t1r + t3i; im[i3] = t1i - t3r; } \
    } while (0)
#define TWM(m, cr, ci) do { \
        f2 rr_ = re[m], ii_ = im[m]; \
        if (SGN < 0) { re[m] = rr_ * (cr) + ii_ * (ci); im[m] = ii_ * (cr) - rr_ * (ci); } \
        else         { re[m] = rr_ * (cr) - ii_ * (ci); im[m] = ii_ * (cr) + rr_ * (ci); } \
    } while (0)
    if (!PERMIN) { BF4(0, 4, 8, 12); BF4(1, 5, 9, 13); BF4(2, 6, 10, 14); BF4(3, 7, 11, 15); }
    else         { BF4(0, 1, 2, 3);  BF4(4, 5, 6, 7);  BF4(8, 9, 10, 11); BF4(12, 13, 14, 15); }
    TWM(5,  C1, S1);    // w1
    TWM(6,  R2, R2);    // w2
    TWM(7,  S1, C1);    // w3
    TWM(9,  R2, R2);    // w2
    {   // x[10] *= S*i : re' = -S*im, im' = S*re
        f2 rr_ = re[10], ii_ = im[10];
        if (SGN < 0) { re[10] = ii_; im[10] = mk2(0.f, 0.f) - rr_; }
        else         { re[10] = mk2(0.f, 0.f) - ii_; im[10] = rr_; }
    }
    TWM(11, -R2, R2);   // w6
    TWM(13, S1, C1);    // w3
    TWM(14, -R2, R2);   // w6
    TWM(15, -C1, -S1);  // w9
    if (!PERMIN) { BF4(0, 1, 2, 3);  BF4(4, 5, 6, 7);  BF4(8, 9, 10, 11); BF4(12, 13, 14, 15); }
    else         { BF4(0, 4, 8, 12); BF4(1, 5, 9, 13); BF4(2, 6, 10, 14); BF4(3, 7, 11, 15); }
#undef BF4
#undef TWM
}

typedef float cplx __attribute__((ext_vector_type(2)));
// d_ws: twA[4096] = W4096^(t*r) at [r*256+t]; twB[256] = W256^(j*r) at [r*16+j]
__global__ void twiddle_init(cplx* __restrict__ twA, cplx* __restrict__ twB) {
    int m = blockIdx.x * NT + threadIdx.x;   // 0..4351
    if (m >= 4352) return;
    float s, c;
    if (m < 4096) {
        int r = m >> 8, t = m & 255;
        sincosf(-6.28318530717958647692f * (float)(t * r) / 4096.0f, &s, &c);
        cplx v; v.x = c; v.y = s; twA[m] = v;
    } else {
        int k = m - 4096;                    // k = r*16 + j
        int r = k >> 4, j = k & 15;
        sincosf(-6.28318530717958647692f * (float)(j * r) / 256.0f, &s, &c);
        cplx v; v.x = c; v.y = s; twB[k] = v;
    }
}

__global__ __launch_bounds__(NT) void circconv4096_kernel(
    const float* __restrict__ A, const float* __restrict__ Bv,
    float* __restrict__ O,
    const cplx* __restrict__ twA, const cplx* __restrict__ twB)
{
    // two rows per block, row-packed 4xf16 per element (b64), XOR swizzle, NO pad:
    // exactly 32 KB -> 5 blocks/CU (was 4 with the additive pad)
    __shared__ h4 Z[FFT_N];
    const int t = threadIdx.x;
    const size_t r0 = (size_t)blockIdx.x * 2;
    const float* a0 = A + r0 * FFT_N;
    const float* b0 = Bv + r0 * FFT_N;
    const float* a1 = a0 + FFT_N;
    const float* b1 = b0 + FFT_N;
    float* o0 = O + r0 * FFT_N;
    float* o1 = o0 + FFT_N;

    f2 re[16], im[16];

#define TWF(m, w) do { f2 rr_ = re[m], ii_ = im[m]; float wr_ = (w).x, wi_ = (w).y; \
        re[m] = rr_ * wr_ - ii_ * wi_; im[m] = rr_ * wi_ + ii_ * wr_; } while (0)
#define TWC(m, w) do { f2 rr_ = re[m], ii_ = im[m]; float wr_ = (w).x, wi_ = (w).y; \
        re[m] = rr_ * wr_ + ii_ * wi_; im[m] = ii_ * wr_ - rr_ * wi_; } while (0)

    // ---- fwd stage 1 (stride 256): coalesced loads, both rows ----
#pragma unroll
    for (int q = 0; q < 16; ++q) {
        int g = t + 256 * q;
        re[q] = mk2(a0[g], a1[g]);
        im[q] = mk2(b0[g], b1[g]);   // z = a + i*b per row
    }
    ip16<-1, false>(re, im);
#pragma unroll
    for (int m = 1; m < 16; ++m) { cplx w = twA[PM(m) * 256 + t]; TWF(m, w); }
#pragma unroll
    for (int m = 0; m < 16; ++m) Z[XS(t + 256 * PM(m))] = packh(re[m], im[m]);
    __syncthreads();

    // ---- middle stages wave-private: wave w owns elements [1024w, 1024w+1024) ----
    const int j = t & 15;
    const int base = ((t >> 4) << 8) + j;

    // ---- fwd stage 2 (stride 16) ----
#pragma unroll
    for (int q = 0; q < 16; ++q) {
        h4 v = Z[XS(base + 16 * q)];
        re[q] = mk2((float)v.x, (float)v.y); im[q] = mk2((float)v.z, (float)v.w);
    }
    ip16<-1, false>(re, im);
#pragma unroll
    for (int m = 1; m < 16; ++m) { cplx w = twB[PM(m) * 16 + j]; TWF(m, w); }
    __builtin_amdgcn_wave_barrier();
#pragma unroll
    for (int m = 0; m < 16; ++m) Z[XS(base + 16 * PM(m))] = packh(re[m], im[m]);
    __builtin_amdgcn_wave_barrier();

    // ---- fwd stage 3 (contig) + scaled square + inv stage 1 (contig) ----
    {
        const int b3 = t * 16;
        const float s = 1.0f / 8192.0f;   // fold /4096 (ifft) and /2 (imag trick)
#pragma unroll
        for (int q = 0; q < 16; ++q) {
            h4 v = Z[XS(b3 + q)];
            re[q] = mk2((float)v.x, (float)v.y); im[q] = mk2((float)v.z, (float)v.w);
        }
        ip16<-1, false>(re, im);
#pragma unroll
        for (int m = 0; m < 16; ++m) {
            f2 r = re[m], i = im[m];
            re[m] = (r * r - i * i) * s;      // (re^2 - im^2) * s, both rows
            im[m] = (r * i) * (2.0f * s);     // 2*s*re*im, both rows
        }
        ip16<1, true>(re, im);
        __builtin_amdgcn_wave_barrier();
#pragma unroll
        for (int q = 0; q < 16; ++q) Z[XS(b3 + q)] = packh(re[q], im[q]);
        __builtin_amdgcn_wave_barrier();
    }

    // ---- inv stage 2 (stride 16): conj twiddle, inverse dft ----
#pragma unroll
    for (int q = 0; q < 16; ++q) {
        h4 v = Z[XS(base + 16 * q)];
        re[q] = mk2((float)v.x, (float)v.y); im[q] = mk2((float)v.z, (float)v.w);
    }
#pragma unroll
    for (int q = 1; q < 16; ++q) { cplx w = twB[q * 16 + j]; TWC(q, w); }
    ip16<1, false>(re, im);
    __builtin_amdgcn_wave_barrier();
#pragma unroll
    for (int m = 0; m < 16; ++m) Z[XS(base + 16 * PM(m))] = packh(re[m], im[m]);
    __syncthreads();   // next stage is stride-256: cross-wave

    // ---- inv stage 3 (stride 256) + coalesced store (normalization folded) ----
#pragma unroll
    for (int q = 0; q < 16; ++q) {
        h4 v = Z[XS(t + 256 * q)];
        re[q] = mk2((float)v.x, (float)v.y); im[q] = mk2((float)v.z, (float)v.w);
    }
#pragma unroll
    for (int q = 1; q < 16; ++q) { cplx w = twA[q * 256 + t]; TWC(q, w); }
    ip16<1, false>(re, im);
#pragma unroll
    for (int m = 0; m < 16; ++m) {
        int idx = t + 256 * PM(m);
        o0[idx] = im[m].x;
        o1[idx] = im[m].y;
    }
#undef TWF
#undef TWC
}

extern "C" void kernel_launch(void* const* d_in, const int* in_sizes, int n_in,
                              void* d_out, int out_size, void* d_ws, size_t ws_size,
                              hipStream_t stream) {
    const float* a = (const float*)d_in[0];
    const float* b = (const float*)d_in[1];
    float* out = (float*)d_out;
    cplx* twA = (cplx*)d_ws;              // 4096 cplx
    cplx* twB = twA + 4096;               // 256 cplx  (total 34 KB)
    const int B = in_sizes[0] / FFT_N;    // 8192 rows

    twiddle_init<<<17, NT, 0, stream>>>(twA, twB);        // 4352 entries
    circconv4096_kernel<<<B / 2, NT, 0, stream>>>(a, b, out, twA, twB);
}

// Round 22
// 102.394 us; speedup vs baseline: 1.0366x; 1.0282x over previous
//
#include <hip/hip_runtime.h>

#define FFT_N 4096
#define NT    256
// additive skew in 8-byte units: +1 per 16 (r19-verified: conflicts ~0.5e6)
#define SK(i) ((i) + ((i) >> 4))
// base-4 digit-reverse involution for 16: P(m) = ((m&3)<<2)|(m>>2)
#define PM(m) ((((m) & 3) << 2) | ((m) >> 2))

typedef float  f2  __attribute__((ext_vector_type(2)));  // lane = row: (row0, row1)
typedef __fp16 h2v __attribute__((ext_vector_type(2)));
typedef __fp16 h4  __attribute__((ext_vector_type(4)));  // LDS: re0, re1, im0, im1

__device__ __forceinline__ f2 mk2(float a, float b) { f2 v; v.x = a; v.y = b; return v; }
__device__ __forceinline__ h4 packh(f2 re, f2 im) {
    h2v r = __builtin_amdgcn_cvt_pkrtz(re.x, re.y);   // 1 op
    h2v i = __builtin_amdgcn_cvt_pkrtz(im.x, im.y);   // 1 op
    h4 v; v.x = r.x; v.y = r.y; v.z = i.x; v.w = i.y;
    return v;
}

// In-place 16-point DFT, SoA over rows: re[m]/im[m] are (row0,row1) pairs.
// Every add/sub/mul is a packed VOP3P op covering both rows (verified r18/r19).
// PERMIN=false: natural in, slot m holds freq PM(m). PERMIN=true: mirrored.
template <int SGN, bool PERMIN>
__device__ __forceinline__ void ip16(f2* re, f2* im) {
    const float C1 = 0.92387953251128675613f;   // cos(pi/8)
    const float S1 = 0.38268343236508977173f;   // sin(pi/8)
    const float R2 = 0.70710678118654752440f;   // sqrt(2)/2
#define BF4(i0, i1, i2, i3) do { \
        f2 t0r = re[i0] + re[i2], t0i = im[i0] + im[i2]; \
        f2 t1r = re[i0] - re[i2], t1i = im[i0] - im[i2]; \
        f2 t2r = re[i1] + re[i3], t2i = im[i1] + im[i3]; \
        f2 t3r = re[i1] - re[i3], t3i = im[i1] - im[i3]; \
        re[i0] = t0r + t2r; im[i0] = t0i + t2i; \
        re[i2] = t0r - t2r; im[i2] = t0i - t2i; \
        if (SGN < 0) { re[i1] = t1r + t3i; im[i1] = t1i - t3r; \
                       re[i3] = t1r - t3i; im[i3] = t1i + t3r; } \
        else         { re[i1] = t1r - t3i; im[i1] = t1i + t3r; \
                       re[i3] = t1r + t3i; im[i3] = t1i - t3r; } \
    } while (0)
#define TWM(m, cr, ci) do { \
        f2 rr_ = re[m], ii_ = im[m]; \
        if (SGN < 0) { re[m] = rr_ * (cr) + ii_ * (ci); im[m] = ii_ * (cr) - rr_ * (ci); } \
        else         { re[m] = rr_ * (cr) - ii_ * (ci); im[m] = ii_ * (cr) + rr_ * (ci); } \
    } while (0)
    if (!PERMIN) { BF4(0, 4, 8, 12); BF4(1, 5, 9, 13); BF4(2, 6, 10, 14); BF4(3, 7, 11, 15); }
    else         { BF4(0, 1, 2, 3);  BF4(4, 5, 6, 7);  BF4(8, 9, 10, 11); BF4(12, 13, 14, 15); }
    TWM(5,  C1, S1);    // w1
    TWM(6,  R2, R2);    // w2
    TWM(7,  S1, C1);    // w3
    TWM(9,  R2, R2);    // w2
    {   // x[10] *= S*i : re' = -S*im, im' = S*re
        f2 rr_ = re[10], ii_ = im[10];
        if (SGN < 0) { re[10] = ii_; im[10] = mk2(0.f, 0.f) - rr_; }
        else         { re[10] = mk2(0.f, 0.f) - ii_; im[10] = rr_; }
    }
    TWM(11, -R2, R2);   // w6
    TWM(13, S1, C1);    // w3
    TWM(14, -R2, R2);   // w6
    TWM(15, -C1, -S1);  // w9
    if (!PERMIN) { BF4(0, 1, 2, 3);  BF4(4, 5, 6, 7);  BF4(8, 9, 10, 11); BF4(12, 13, 14, 15); }
    else         { BF4(0, 4, 8, 12); BF4(1, 5, 9, 13); BF4(2, 6, 10, 14); BF4(3, 7, 11, 15); }
#undef BF4
#undef TWM
}

typedef float cplx __attribute__((ext_vector_type(2)));
// d_ws: twA[4096] = W4096^(t*r) at [r*256+t]; twB[256] = W256^(j*r) at [r*16+j]
__global__ void twiddle_init(cplx* __restrict__ twA, cplx* __restrict__ twB) {
    int m = blockIdx.x * NT + threadIdx.x;   // 0..4351
    if (m >= 4352) return;
    float s, c;
    if (m < 4096) {
        int r = m >> 8, t = m & 255;
        sincosf(-6.28318530717958647692f * (float)(t * r) / 4096.0f, &s, &c);
        cplx v; v.x = c; v.y = s; twA[m] = v;
    } else {
        int k = m - 4096;                    // k = r*16 + j
        int r = k >> 4, j = k & 15;
        sincosf(-6.28318530717958647692f * (float)(j * r) / 256.0f, &s, &c);
        cplx v; v.x = c; v.y = s; twB[k] = v;
    }
}

__global__ __launch_bounds__(NT) void circconv4096_kernel(
    const float* __restrict__ A, const float* __restrict__ Bv,
    float* __restrict__ O,
    const cplx* __restrict__ twA, const cplx* __restrict__ twB)
{
    // two rows per block, row-packed 4xf16 per element (b64): 34.8 KB -> 4 blocks/CU
    __shared__ h4 Z[SK(4095) + 1];
    const int t = threadIdx.x;
    const size_t r0 = (size_t)blockIdx.x * 2;
    const float* a0 = A + r0 * FFT_N;
    const float* b0 = Bv + r0 * FFT_N;
    const float* a1 = a0 + FFT_N;
    const float* b1 = b0 + FFT_N;
    float* o0 = O + r0 * FFT_N;
    float* o1 = o0 + FFT_N;

    f2 re[16], im[16];

#define TWF(m, w) do { f2 rr_ = re[m], ii_ = im[m]; float wr_ = (w).x, wi_ = (w).y; \
        re[m] = rr_ * wr_ - ii_ * wi_; im[m] = rr_ * wi_ + ii_ * wr_; } while (0)
#define TWC(m, w) do { f2 rr_ = re[m], ii_ = im[m]; float wr_ = (w).x, wi_ = (w).y; \
        re[m] = rr_ * wr_ + ii_ * wi_; im[m] = ii_ * wr_ - rr_ * wi_; } while (0)

    const int j = t & 15;
    const int base = ((t >> 4) << 8) + j;

    // ---- fwd stage 1 (stride 256): coalesced loads, both rows ----
#pragma unroll
    for (int q = 0; q < 16; ++q) {
        int g = t + 256 * q;
        re[q] = mk2(a0[g], a1[g]);
        im[q] = mk2(b0[g], b1[g]);   // z = a + i*b per row
    }
    // PREFETCH twB set before the barrier: used by fwd2 (PM order) AND inv2 (natural)
    cplx wB[15];
#pragma unroll
    for (int q = 1; q < 16; ++q) wB[q - 1] = twB[q * 16 + j];

    ip16<-1, false>(re, im);
#pragma unroll
    for (int m = 1; m < 16; ++m) { cplx w = twA[PM(m) * 256 + t]; TWF(m, w); }
#pragma unroll
    for (int m = 0; m < 16; ++m) Z[SK(t + 256 * PM(m))] = packh(re[m], im[m]);
    __syncthreads();

    // ---- fwd stage 2 (stride 16, wave-private): twiddles already in registers ----
#pragma unroll
    for (int q = 0; q < 16; ++q) {
        h4 v = Z[SK(base + 16 * q)];
        re[q] = mk2((float)v.x, (float)v.y); im[q] = mk2((float)v.z, (float)v.w);
    }
    ip16<-1, false>(re, im);
#pragma unroll
    for (int m = 1; m < 16; ++m) TWF(m, wB[PM(m) - 1]);
    __builtin_amdgcn_wave_barrier();
#pragma unroll
    for (int m = 0; m < 16; ++m) Z[SK(base + 16 * PM(m))] = packh(re[m], im[m]);
    __builtin_amdgcn_wave_barrier();

    // ---- fwd stage 3 (contig) + scaled square + inv stage 1 (contig) ----
    {
        const int b3 = t * 16;
        const float s = 1.0f / 8192.0f;   // fold /4096 (ifft) and /2 (imag trick)
#pragma unroll
        for (int q = 0; q < 16; ++q) {
            h4 v = Z[SK(b3 + q)];
            re[q] = mk2((float)v.x, (float)v.y); im[q] = mk2((float)v.z, (float)v.w);
        }
        ip16<-1, false>(re, im);
#pragma unroll
        for (int m = 0; m < 16; ++m) {
            f2 r = re[m], i = im[m];
            re[m] = (r * r - i * i) * s;      // (re^2 - im^2) * s, both rows
            im[m] = (r * i) * (2.0f * s);     // 2*s*re*im, both rows
        }
        ip16<1, true>(re, im);
        __builtin_amdgcn_wave_barrier();
#pragma unroll
        for (int q = 0; q < 16; ++q) Z[SK(b3 + q)] = packh(re[q], im[q]);
        __builtin_amdgcn_wave_barrier();
    }

    // ---- inv stage 2 (stride 16): conj twiddle from registers, inverse dft ----
#pragma unroll
    for (int q = 0; q < 16; ++q) {
        h4 v = Z[SK(base + 16 * q)];
        re[q] = mk2((float)v.x, (float)v.y); im[q] = mk2((float)v.z, (float)v.w);
    }
#pragma unroll
    for (int q = 1; q < 16; ++q) TWC(q, wB[q - 1]);
    // PREFETCH inv3's twA set now (wB dead): latency hides under ip16 + barrier
    cplx wA2[15];
#pragma unroll
    for (int q = 1; q < 16; ++q) wA2[q - 1] = twA[q * 256 + t];
    ip16<1, false>(re, im);
    __builtin_amdgcn_wave_barrier();
#pragma unroll
    for (int m = 0; m < 16; ++m) Z[SK(base + 16 * PM(m))] = packh(re[m], im[m]);
    __syncthreads();   // next stage is stride-256: cross-wave

    // ---- inv stage 3 (stride 256) + coalesced store (normalization folded) ----
#pragma unroll
    for (int q = 0; q < 16; ++q) {
        h4 v = Z[SK(t + 256 * q)];
        re[q] = mk2((float)v.x, (float)v.y); im[q] = mk2((float)v.z, (float)v.w);
    }
#pragma unroll
    for (int q = 1; q < 16; ++q) TWC(q, wA2[q - 1]);
    ip16<1, false>(re, im);
#pragma unroll
    for (int m = 0; m < 16; ++m) {
        int idx = t + 256 * PM(m);
        o0[idx] = im[m].x;
        o1[idx] = im[m].y;
    }
#undef TWF
#undef TWC
}

extern "C" void kernel_launch(void* const* d_in, const int* in_sizes, int n_in,
                              void* d_out, int out_size, void* d_ws, size_t ws_size,
                              hipStream_t stream) {
    const float* a = (const float*)d_in[0];
    const float* b = (const float*)d_in[1];
    float* out = (float*)d_out;
    cplx* twA = (cplx*)d_ws;              // 4096 cplx
    cplx* twB = twA + 4096;               // 256 cplx  (total 34 KB)
    const int B = in_sizes[0] / FFT_N;    // 8192 rows

    twiddle_init<<<17, NT, 0, stream>>>(twA, twB);        // 4352 entries
    circconv4096_kernel<<<B / 2, NT, 0, stream>>>(a, b, out, twA, twB);
}